// Round 9
// baseline (1037.788 us; speedup 1.0000x reference)
//
#include <hip/hip_runtime.h>

#define N_NODES 50000
#define E_EDGES 800000
#define IN_F    128
#define H_F     64
#define STD_EPS 1e-5f
#define BN_EPS  1e-5f

#define HIST_BLK 3125   // E_EDGES / 256 exactly
#define EMB_BLK  768
#define SCAN_BLK 49
#define TRANS_BLK 448   // 114688 / 256

// ------------------------------------------- fused degree hist + embed GEMM
// blocks [0, HIST_BLK): histogram of dst.  blocks [HIST_BLK, +EMB_BLK):
// h = x @ embed_W + b (32-node groups, 8 nodes/thread).  Independent work,
// co-resident -> embed hides under hist's atomic latency.
__global__ __launch_bounds__(256) void k_hist_embed(const int* __restrict__ dst,
                                                    int* __restrict__ deg,
                                                    const float* __restrict__ x,
                                                    const float* __restrict__ W,
                                                    const float* __restrict__ bias,
                                                    float* __restrict__ h) {
  __shared__ float sW[IN_F * 64];    // 32 KB
  __shared__ float sx[IN_F * 36];    // x_T[k][32+pad4] 18 KB
  if (blockIdx.x < HIST_BLK) {
    int e = blockIdx.x * 256 + threadIdx.x;
    atomicAdd(&deg[dst[e]], 1);      // grid sized so e < E_EDGES always
    return;
  }
  for (int i = threadIdx.x; i < IN_F * 64; i += 256) sW[i] = W[i];
  int f = threadIdx.x & 63, ng = threadIdx.x >> 6;
  float bj = bias[f];
  const int NGRP = (N_NODES + 31) / 32;   // 1563
  for (int grp = blockIdx.x - HIST_BLK; grp < NGRP; grp += EMB_BLK) {
    int n0 = grp * 32;
    __syncthreads();
    for (int idx = threadIdx.x; idx < 32 * IN_F; idx += 256) {
      int nl = idx >> 7, k = idx & 127;
      int n = n0 + nl;
      sx[k * 36 + nl] = (n < N_NODES) ? x[(size_t)n * IN_F + k] : 0.f;
    }
    __syncthreads();
    float a[8] = {bj, bj, bj, bj, bj, bj, bj, bj};
    const float* xp = &sx[ng * 8];
#pragma unroll 4
    for (int k = 0; k < IN_F; k++) {
      float4 h0 = *(const float4*)&xp[k * 36];
      float4 h1 = *(const float4*)&xp[k * 36 + 4];
      float w = sW[k * 64 + f];
      a[0] = fmaf(h0.x, w, a[0]); a[1] = fmaf(h0.y, w, a[1]);
      a[2] = fmaf(h0.z, w, a[2]); a[3] = fmaf(h0.w, w, a[3]);
      a[4] = fmaf(h1.x, w, a[4]); a[5] = fmaf(h1.y, w, a[5]);
      a[6] = fmaf(h1.z, w, a[6]); a[7] = fmaf(h1.w, w, a[7]);
    }
#pragma unroll
    for (int j = 0; j < 8; j++) {
      int n = n0 + ng * 8 + j;
      if (n < N_NODES) h[(size_t)n * 64 + f] = a[j];
    }
  }
}

// --------------------- fused scan phase-1 (+ sum log(deg+1)) and transpose
// blocks [0, SCAN_BLK): per-1024-chunk degree sums + log-sum.
// blocks [SCAN_BLK, +TRANS_BLK): pack-transpose postW/linW (one-off).
// postWT[l][t][fb][g][4j]  <- postW_l[t*26624 + (fb*4+j)*32 + g]
// linWT[l][c4][col][4j]    <- linW_l[(c4*4+j)*64 + col]
__global__ __launch_bounds__(256) void k_scanpart_trans(const int* __restrict__ deg,
                                                        int* __restrict__ partials,
                                                        float* __restrict__ scalars,
                                                        const float* __restrict__ pW1,
                                                        const float* __restrict__ pW2,
                                                        const float* __restrict__ lW1,
                                                        const float* __restrict__ lW2,
                                                        float* __restrict__ pWT,
                                                        float* __restrict__ lWT) {
  __shared__ int red[256];
  __shared__ float redf[256];
  if (blockIdx.x < SCAN_BLK) {
    int base = blockIdx.x * 1024;
    int s = 0; float ls = 0.f;
    for (int j = threadIdx.x; j < 1024; j += 256) {
      int i = base + j;
      if (i < N_NODES) { int d = deg[i]; s += d; ls += logf((float)d + 1.0f); }
    }
    red[threadIdx.x] = s; redf[threadIdx.x] = ls; __syncthreads();
    for (int st = 128; st > 0; st >>= 1) {
      if (threadIdx.x < st) {
        red[threadIdx.x] += red[threadIdx.x + st];
        redf[threadIdx.x] += redf[threadIdx.x + st];
      }
      __syncthreads();
    }
    if (threadIdx.x == 0) {
      partials[blockIdx.x] = red[0];
      atomicAdd(&scalars[0], redf[0]);
    }
    return;
  }
  int idx = (blockIdx.x - SCAN_BLK) * 256 + threadIdx.x;
  if (idx < 106496) {
    int layer = idx / 53248, r = idx % 53248;
    int t = r / 26624, r2 = r % 26624;
    int fb = r2 / 128, r3 = r2 % 128;
    int g = r3 / 4, j = r3 % 4;
    const float* srcp = layer ? pW2 : pW1;
    pWT[idx] = srcp[(size_t)t * 26624 + (fb * 4 + j) * 32 + g];
  } else if (idx < 114688) {
    int jj = idx - 106496;
    int layer = jj / 4096, r2 = jj % 4096;
    int c4 = r2 / 256, r3 = r2 % 256;
    int col = r3 / 4, j = r3 % 4;
    const float* srcl = layer ? lW2 : lW1;
    lWT[jj] = srcl[(c4 * 4 + j) * 64 + col];
  }
}

// ----------------------- scan final (self-computed prefix, no mid kernel)
__global__ __launch_bounds__(256) void k_scan_final(const int* __restrict__ deg,
                                                    const int* __restrict__ partials,
                                                    int* __restrict__ row_ptr,
                                                    int* __restrict__ cursor,
                                                    float* __restrict__ scalars) {
  __shared__ int ts[256];
  __shared__ int sbase;
  if (threadIdx.x == 0) {
    int pre = 0;
    for (int b = 0; b < (int)blockIdx.x; b++) pre += partials[b];
    sbase = pre;
    if (blockIdx.x == 0) {
      scalars[1] = scalars[0] / (float)N_NODES;   // avg_log
      row_ptr[N_NODES] = E_EDGES;
    }
  }
  int base = blockIdx.x * 1024 + threadIdx.x * 4;
  int d[4]; int s = 0;
#pragma unroll
  for (int j = 0; j < 4; j++) {
    int i = base + j;
    d[j] = (i < N_NODES) ? deg[i] : 0;
    s += d[j];
  }
  ts[threadIdx.x] = s; __syncthreads();
  for (int off = 1; off < 256; off <<= 1) {
    int t = (threadIdx.x >= off) ? ts[threadIdx.x - off] : 0;
    __syncthreads();
    ts[threadIdx.x] += t;
    __syncthreads();
  }
  int excl = (threadIdx.x > 0) ? ts[threadIdx.x - 1] : 0;
  int run = sbase + excl;
#pragma unroll
  for (int j = 0; j < 4; j++) {
    int i = base + j;
    if (i < N_NODES) { row_ptr[i] = run; cursor[i] = run; run += d[j]; }
  }
}

// ------------------------------------------------------------------- scatter
__global__ __launch_bounds__(256) void k_scatter(const int* __restrict__ src,
                                                 const int* __restrict__ dst,
                                                 int* __restrict__ cursor,
                                                 int* __restrict__ csr_src) {
  int e = blockIdx.x * 256 + threadIdx.x;
  if (e < E_EDGES) {
    int d = dst[e];
    int p = atomicAdd(&cursor[d], 1);
    csr_src[p] = src[e];
  }
}

// ------------------------------------------------------------------ pre A/B
// One TOWER per block (t = blockIdx.x & 1).  64-node groups, 16 nodes/thread.
// Weights packed interleaved: sWp[k*128 + f*2 + {0,1}] = {Wa[k,f], Wb[k,f]}.
// BN variant computes scale/shift itself from bnsum/bnsumsq (no k_bnfin).
template <bool BN>
__global__ __launch_bounds__(256) void k_preab(const float* __restrict__ hin,
                                               const float* __restrict__ preW,
                                               const float* __restrict__ preb,
                                               const float* __restrict__ bnsum,
                                               const float* __restrict__ bnsumsq,
                                               const float* __restrict__ gamma,
                                               const float* __restrict__ beta,
                                               float* __restrict__ h2out,
                                               float* __restrict__ hA,
                                               float* __restrict__ hB) {
  __shared__ float sWp[64 * 128];   // 32 KB packed [k][f][{A,B}]
  __shared__ float sh[64 * 68];     // h_T[k][64+pad4]  17408 B
  __shared__ float sbn[128];        // scale[64], shift[64]
  int t = blockIdx.x & 1;
  const float* Wsrc = preW + (size_t)t * 128 * 64;
  for (int i = threadIdx.x; i < 64 * 64; i += 256) {
    int k = i >> 6, f = i & 63;
    float wa = Wsrc[k * 64 + f];
    float wb = Wsrc[(64 + k) * 64 + f];
    *(float2*)&sWp[k * 128 + f * 2] = make_float2(wa, wb);
  }
  if (BN && threadIdx.x < 64) {
    int c = threadIdx.x;
    float mu = bnsum[c] * (1.f / N_NODES);
    float var = bnsumsq[c] * (1.f / N_NODES) - mu * mu;
    float sc = gamma[c] / sqrtf(var + BN_EPS);
    sbn[c] = sc;
    sbn[64 + c] = fmaf(-mu, sc, beta[c]);
  }
  int f = threadIdx.x & 63, ng = threadIdx.x >> 6;   // ng 0..3 -> 16 nodes each
  float pb = preb[t * 64 + f];
  int nblk2 = gridDim.x >> 1;
  const int NGRP = (N_NODES + 63) / 64;   // 782
  for (int grp = blockIdx.x >> 1; grp < NGRP; grp += nblk2) {
    int n0 = grp * 64;
    __syncthreads();
    for (int idx = threadIdx.x; idx < 64 * 64; idx += 256) {
      int nl = idx >> 6, k = idx & 63;
      int n = n0 + nl;
      float v = 0.f;
      if (n < N_NODES) {
        v = hin[(size_t)n * 64 + k];
        if (BN) {
          v = fmaxf(fmaf(v, sbn[k], sbn[64 + k]), 0.f);
          if (t == 0) h2out[(size_t)n * 64 + k] = v;
        }
      }
      sh[k * 68 + nl] = v;
    }
    __syncthreads();
    float a[16], b[16];
#pragma unroll
    for (int j = 0; j < 16; j++) { a[j] = pb; b[j] = 0.f; }
    const float* hp = &sh[ng * 16];
    const float* wp = &sWp[f * 2];
#pragma unroll 2
    for (int k = 0; k < 64; k++) {
      float4 h0 = *(const float4*)&hp[k * 68];
      float4 h1 = *(const float4*)&hp[k * 68 + 4];
      float4 h2 = *(const float4*)&hp[k * 68 + 8];
      float4 h3 = *(const float4*)&hp[k * 68 + 12];
      float2 w2 = *(const float2*)&wp[k * 128];
      a[0]  = fmaf(h0.x, w2.x, a[0]);  b[0]  = fmaf(h0.x, w2.y, b[0]);
      a[1]  = fmaf(h0.y, w2.x, a[1]);  b[1]  = fmaf(h0.y, w2.y, b[1]);
      a[2]  = fmaf(h0.z, w2.x, a[2]);  b[2]  = fmaf(h0.z, w2.y, b[2]);
      a[3]  = fmaf(h0.w, w2.x, a[3]);  b[3]  = fmaf(h0.w, w2.y, b[3]);
      a[4]  = fmaf(h1.x, w2.x, a[4]);  b[4]  = fmaf(h1.x, w2.y, b[4]);
      a[5]  = fmaf(h1.y, w2.x, a[5]);  b[5]  = fmaf(h1.y, w2.y, b[5]);
      a[6]  = fmaf(h1.z, w2.x, a[6]);  b[6]  = fmaf(h1.z, w2.y, b[6]);
      a[7]  = fmaf(h1.w, w2.x, a[7]);  b[7]  = fmaf(h1.w, w2.y, b[7]);
      a[8]  = fmaf(h2.x, w2.x, a[8]);  b[8]  = fmaf(h2.x, w2.y, b[8]);
      a[9]  = fmaf(h2.y, w2.x, a[9]);  b[9]  = fmaf(h2.y, w2.y, b[9]);
      a[10] = fmaf(h2.z, w2.x, a[10]); b[10] = fmaf(h2.z, w2.y, b[10]);
      a[11] = fmaf(h2.w, w2.x, a[11]); b[11] = fmaf(h2.w, w2.y, b[11]);
      a[12] = fmaf(h3.x, w2.x, a[12]); b[12] = fmaf(h3.x, w2.y, b[12]);
      a[13] = fmaf(h3.y, w2.x, a[13]); b[13] = fmaf(h3.y, w2.y, b[13]);
      a[14] = fmaf(h3.z, w2.x, a[14]); b[14] = fmaf(h3.z, w2.y, b[14]);
      a[15] = fmaf(h3.w, w2.x, a[15]); b[15] = fmaf(h3.w, w2.y, b[15]);
    }
    int tf = t * 64 + f;
#pragma unroll
    for (int j = 0; j < 16; j++) {
      int n = n0 + ng * 16 + j;
      if (n < N_NODES) {
        hA[(size_t)n * 128 + tf] = a[j];
        hB[(size_t)n * 128 + tf] = b[j];
      }
    }
  }
}

// --------------------------------------------------- fused conv main kernel
// 8 nodes/block, 20.5 KB LDS, 7 blocks/CU.  Weights from packed transposed
// postWT (lane g reads dwordx4 of 4 consecutive-f13 weights, coalesced).
// BNACC variant fuses BN-stats accumulation into the epilogue (no k_bnstats).
template <bool BNACC>
__global__ __launch_bounds__(256, 7) void k_conv(const float* __restrict__ hA,
                                                 const float* __restrict__ hB,
                                                 const float* __restrict__ hskip,
                                                 const int* __restrict__ row_ptr,
                                                 const int* __restrict__ csr_src,
                                                 const float* __restrict__ postWT,
                                                 const float* __restrict__ postb,
                                                 const float* __restrict__ linWT,
                                                 const float* __restrict__ linb,
                                                 const float* __restrict__ scalars,
                                                 float* __restrict__ out,
                                                 float* __restrict__ bnsum,
                                                 float* __restrict__ bnsumsq) {
  __shared__ float sm[2 * 5 * 8 * 64];   // 20480 B; [(t*5+feat)*512 + node*64 + hf]
  __shared__ float sAB[16];              // sA[0..7], sB[8..15]
  int w = threadIdx.x >> 6, lane = threadIdx.x & 63;
  int n0 = blockIdx.x * 8;
  int t = lane >> 5, fb2 = (lane & 31) * 2;
  int off = t * 64 + fb2;
  float avg = scalars[1];

  // ---- phase A: aggregation, 2 nodes per wave, 4 loads in flight
#pragma unroll 1
  for (int k = 0; k < 2; k++) {
    int nl = w * 2 + k;
    int n = n0 + nl;
    float2 a = *(const float2*)&hA[(size_t)n * 128 + off];
    int rp0 = __builtin_amdgcn_readfirstlane(row_ptr[n]);
    int rp1 = __builtin_amdgcn_readfirstlane(row_ptr[n + 1]);
    float sx0=0,sy0=0,qx0=0,qy0=0, sx1=0,sy1=0,qx1=0,qy1=0;
    float mnx0=INFINITY,mny0=INFINITY,mxx0=-INFINITY,mxy0=-INFINITY;
    float mnx1=INFINITY,mny1=INFINITY,mxx1=-INFINITY,mxy1=-INFINITY;
    int i = rp0;
    int end4 = rp0 + ((rp1 - rp0) & ~3);
    if (i < end4) {
      int s0 = csr_src[i], s1 = csr_src[i+1], s2 = csr_src[i+2], s3 = csr_src[i+3];
      while (true) {
        float2 v0 = *(const float2*)&hB[(size_t)s0 * 128 + off];
        float2 v1 = *(const float2*)&hB[(size_t)s1 * 128 + off];
        float2 v2 = *(const float2*)&hB[(size_t)s2 * 128 + off];
        float2 v3 = *(const float2*)&hB[(size_t)s3 * 128 + off];
        i += 4;
        bool more = (i < end4);
        if (more) { s0 = csr_src[i]; s1 = csr_src[i+1]; s2 = csr_src[i+2]; s3 = csr_src[i+3]; }
        float e0x = v0.x + a.x, e0y = v0.y + a.y;
        float e1x = v1.x + a.x, e1y = v1.y + a.y;
        float e2x = v2.x + a.x, e2y = v2.y + a.y;
        float e3x = v3.x + a.x, e3y = v3.y + a.y;
        sx0 += e0x; qx0 = fmaf(e0x,e0x,qx0); mnx0 = fminf(mnx0,e0x); mxx0 = fmaxf(mxx0,e0x);
        sy0 += e0y; qy0 = fmaf(e0y,e0y,qy0); mny0 = fminf(mny0,e0y); mxy0 = fmaxf(mxy0,e0y);
        sx1 += e1x; qx1 = fmaf(e1x,e1x,qx1); mnx1 = fminf(mnx1,e1x); mxx1 = fmaxf(mxx1,e1x);
        sy1 += e1y; qy1 = fmaf(e1y,e1y,qy1); mny1 = fminf(mny1,e1y); mxy1 = fmaxf(mxy1,e1y);
        sx0 += e2x; qx0 = fmaf(e2x,e2x,qx0); mnx0 = fminf(mnx0,e2x); mxx0 = fmaxf(mxx0,e2x);
        sy0 += e2y; qy0 = fmaf(e2y,e2y,qy0); mny0 = fminf(mny0,e2y); mxy0 = fmaxf(mxy0,e2y);
        sx1 += e3x; qx1 = fmaf(e3x,e3x,qx1); mnx1 = fminf(mnx1,e3x); mxx1 = fmaxf(mxx1,e3x);
        sy1 += e3y; qy1 = fmaf(e3y,e3y,qy1); mny1 = fminf(mny1,e3y); mxy1 = fmaxf(mxy1,e3y);
        if (!more) break;
      }
    }
    {   // masked tail: 0..3 edges, all loads issued together
      int r = rp1 - i;
      if (r > 0) {
        int e1i = (r > 1) ? i + 1 : i;
        int e2i = (r > 2) ? i + 2 : i;
        int t0 = csr_src[i], t1 = csr_src[e1i], t2 = csr_src[e2i];
        float2 u0 = *(const float2*)&hB[(size_t)t0 * 128 + off];
        float2 u1 = *(const float2*)&hB[(size_t)t1 * 128 + off];
        float2 u2 = *(const float2*)&hB[(size_t)t2 * 128 + off];
        float ex = u0.x + a.x, ey = u0.y + a.y;
        sx0 += ex; qx0 = fmaf(ex,ex,qx0); mnx0 = fminf(mnx0,ex); mxx0 = fmaxf(mxx0,ex);
        sy0 += ey; qy0 = fmaf(ey,ey,qy0); mny0 = fminf(mny0,ey); mxy0 = fmaxf(mxy0,ey);
        if (r > 1) {
          ex = u1.x + a.x; ey = u1.y + a.y;
          sx1 += ex; qx1 = fmaf(ex,ex,qx1); mnx1 = fminf(mnx1,ex); mxx1 = fmaxf(mxx1,ex);
          sy1 += ey; qy1 = fmaf(ey,ey,qy1); mny1 = fminf(mny1,ey); mxy1 = fmaxf(mxy1,ey);
        }
        if (r > 2) {
          ex = u2.x + a.x; ey = u2.y + a.y;
          sx0 += ex; qx0 = fmaf(ex,ex,qx0); mnx0 = fminf(mnx0,ex); mxx0 = fmaxf(mxx0,ex);
          sy0 += ey; qy0 = fmaf(ey,ey,qy0); mny0 = fminf(mny0,ey); mxy0 = fmaxf(mxy0,ey);
        }
      }
    }
    int dg = rp1 - rp0;
    float cnt = (float)(dg > 0 ? dg : 1);
    float inv = 1.0f / cnt;
    float meanx = (sx0 + sx1) * inv, meany = (sy0 + sy1) * inv;
    float qx = qx0 + qx1, qy = qy0 + qy1;
    float sdx = sqrtf(fmaxf(qx * inv - meanx * meanx, 0.f) + STD_EPS);
    float sdy = sqrtf(fmaxf(qy * inv - meany * meany, 0.f) + STD_EPS);
    float mnx = fminf(mnx0, mnx1), mny = fminf(mny0, mny1);
    float mxx = fmaxf(mxx0, mxx1), mxy = fmaxf(mxy0, mxy1);
    if (dg == 0) { mnx = 0; mny = 0; mxx = 0; mxy = 0; }
    float ldv = logf(cnt + 1.f);
    float2 hsv = *(const float2*)&hskip[(size_t)n * 64 + fb2];
    // write 5 unique slices
    float* bp = &sm[t * 2560 + nl * 64 + fb2];
    *(float2*)&bp[0]    = hsv;
    *(float2*)&bp[512]  = make_float2(meanx, meany);
    *(float2*)&bp[1024] = make_float2(mnx, mny);
    *(float2*)&bp[1536] = make_float2(mxx, mxy);
    *(float2*)&bp[2048] = make_float2(sdx, sdy);
    if (lane == 0) { sAB[nl] = ldv / avg; sAB[8 + nl] = avg / ldv; }
  }
  __syncthreads();

  // ---- phase C: factored post matmul; wave w covers hf [w*16, w*16+16)
  float g1[8] = {0,0,0,0,0,0,0,0};
  float g2[8] = {0,0,0,0,0,0,0,0};
  float g3[8] = {0,0,0,0,0,0,0,0};
  {
    int g = lane & 31, hf0 = w * 16, fb0 = w * 4;
    const float4* pw4 = (const float4*)postWT + (size_t)t * 6656 + g;
    const float* vb = &sm[t * 2560 + hf0];
    // feat0 = h: G1 only
#pragma unroll
    for (int jj = 0; jj < 4; jj++) {
      float4 wv = pw4[(fb0 + jj) * 32];
#pragma unroll
      for (int nn = 0; nn < 8; nn++) {
        float4 v = *(const float4*)&vb[nn * 64 + jj * 4];
        g1[nn] = fmaf(v.w, wv.w, fmaf(v.z, wv.z, fmaf(v.y, wv.y, fmaf(v.x, wv.x, g1[nn]))));
      }
    }
    // feats 1..4 (agg): fb = 16+fa*16+fb0+jj; G2 at +64 fb, G3 at +128 fb
#pragma unroll
    for (int fa = 0; fa < 4; fa++) {
      const float* vfa = &vb[(1 + fa) * 512];
#pragma unroll
      for (int jj = 0; jj < 4; jj++) {
        int fb = 16 + fa * 16 + fb0 + jj;
        float4 w1v = pw4[fb * 32];
        float4 w2v = pw4[(fb + 64) * 32];
        float4 w3v = pw4[(fb + 128) * 32];
#pragma unroll
        for (int nn = 0; nn < 8; nn++) {
          float4 v = *(const float4*)&vfa[nn * 64 + jj * 4];
          g1[nn] = fmaf(v.w, w1v.w, fmaf(v.z, w1v.z, fmaf(v.y, w1v.y, fmaf(v.x, w1v.x, g1[nn]))));
          g2[nn] = fmaf(v.w, w2v.w, fmaf(v.z, w2v.z, fmaf(v.y, w2v.y, fmaf(v.x, w2v.x, g2[nn]))));
          g3[nn] = fmaf(v.w, w3v.w, fmaf(v.z, w3v.z, fmaf(v.y, w3v.y, fmaf(v.x, w3v.x, g3[nn]))));
        }
      }
    }
  }
  // combine with per-node scalars (sAB reads are broadcast)
  float o8[8];
#pragma unroll
  for (int nn = 0; nn < 8; nn++)
    o8[nn] = fmaf(sAB[8 + nn], g3[nn], fmaf(sAB[nn], g2[nn], g1[nn]));
  __syncthreads();   // all sm reads done -> safe to alias

  // ---- partials into aliased region: lpart[node8][tg64][rep4] = sm[0..2047]
  {
    int sw = (w + (lane >> 4)) & 3;
#pragma unroll
    for (int nn = 0; nn < 8; nn++)
      sm[((nn * 64 + lane) << 2) + sw] = o8[nn];
  }
  __syncthreads();

  // ---- reduce + postb -> po at sm[2048 + node*64 + col]
  {
#pragma unroll
    for (int r = 0; r < 2; r++) {
      int idx = r * 256 + (int)threadIdx.x;
      float4 p = *(const float4*)&sm[idx << 2];
      sm[2048 + idx] = p.x + p.y + p.z + p.w + postb[idx & 63];
    }
  }
  __syncthreads();

  // ---- lin epilogue: wave w -> nodes w*2, w*2+1; col = lane
  {
    float acc0 = linb[lane], acc1 = acc0;
    const float4* lw4 = (const float4*)linWT + lane;
    const float* p0 = &sm[2048 + (w * 2) * 64];
    const float* p1 = p0 + 64;
#pragma unroll
    for (int c4 = 0; c4 < 16; c4++) {
      float4 lwv = lw4[c4 * 64];
      float4 pa = *(const float4*)&p0[c4 * 4];
      float4 pb2 = *(const float4*)&p1[c4 * 4];
      acc0 = fmaf(pa.w, lwv.w, fmaf(pa.z, lwv.z, fmaf(pa.y, lwv.y, fmaf(pa.x, lwv.x, acc0))));
      acc1 = fmaf(pb2.w, lwv.w, fmaf(pb2.z, lwv.z, fmaf(pb2.y, lwv.y, fmaf(pb2.x, lwv.x, acc1))));
    }
    size_t ob = (size_t)(n0 + w * 2) * 64 + lane;
    out[ob] = acc0;
    out[ob + 64] = acc1;
    if (BNACC) {   // fused BN statistics (replaces k_bnstats)
      atomicAdd(&bnsum[lane], acc0 + acc1);
      atomicAdd(&bnsumsq[lane], fmaf(acc0, acc0, acc1 * acc1));
    }
  }
}

// ================================================================== launcher
extern "C" void kernel_launch(void* const* d_in, const int* in_sizes, int n_in,
                              void* d_out, int out_size, void* d_ws, size_t ws_size,
                              hipStream_t stream) {
  const float* x      = (const float*)d_in[0];
  const float* embW   = (const float*)d_in[1];
  const float* embB   = (const float*)d_in[2];
  const float* preW1  = (const float*)d_in[3];
  const float* preb1  = (const float*)d_in[4];
  const float* postW1 = (const float*)d_in[5];
  const float* postb1 = (const float*)d_in[6];
  const float* linW1  = (const float*)d_in[7];
  const float* linb1  = (const float*)d_in[8];
  const float* gamma  = (const float*)d_in[9];
  const float* beta   = (const float*)d_in[10];
  const float* preW2  = (const float*)d_in[11];
  const float* preb2  = (const float*)d_in[12];
  const float* postW2 = (const float*)d_in[13];
  const float* postb2 = (const float*)d_in[14];
  const float* linW2  = (const float*)d_in[15];
  const float* linb2  = (const float*)d_in[16];
  const int*   src    = (const int*)d_in[17];
  const int*   dst    = (const int*)d_in[18];
  float* out = (float*)d_out;

  char* w = (char*)d_ws;
  size_t o = 0;
  int*   deg     = (int*)(w + o);   o += (size_t)N_NODES * 4;
  float* scalars = (float*)(w + o); o += 64;
  float* bnsum   = (float*)(w + o); o += 256;
  float* bnsumsq = (float*)(w + o); o += 256;
  size_t zero_len = o;
  o = (o + 255) & ~(size_t)255;
  int* partials = (int*)(w + o);  o += 256;
  int* row_ptr  = (int*)(w + o);  o += (size_t)(N_NODES + 1) * 4; o = (o + 255) & ~(size_t)255;
  int* cursor   = (int*)(w + o);  o += (size_t)N_NODES * 4;       o = (o + 255) & ~(size_t)255;
  int* csr      = (int*)(w + o);  o += (size_t)E_EDGES * 4;       o = (o + 255) & ~(size_t)255;
  float* postWT = (float*)(w + o); o += (size_t)2 * 53248 * 4;
  float* linWT  = (float*)(w + o); o += (size_t)2 * 4096 * 4;
  float* h1 = (float*)(w + o); o += (size_t)N_NODES * 64 * 4;
  float* y1 = (float*)(w + o); o += (size_t)N_NODES * 64 * 4;
  float* h2 = (float*)(w + o); o += (size_t)N_NODES * 64 * 4;
  float* hA = (float*)(w + o); o += (size_t)N_NODES * 128 * 4;
  float* hB = (float*)(w + o); o += (size_t)N_NODES * 128 * 4;

  hipMemsetAsync(w, 0, zero_len, stream);

  // hist + embed (fused, independent)
  k_hist_embed<<<HIST_BLK + EMB_BLK, 256, 0, stream>>>(dst, deg, x, embW, embB, h1);
  // scan phase 1 + log-sum + weight transpose (fused, independent)
  k_scanpart_trans<<<SCAN_BLK + TRANS_BLK, 256, 0, stream>>>(
      deg, partials, scalars, postW1, postW2, linW1, linW2, postWT, linWT);
  k_scan_final<<<SCAN_BLK, 256, 0, stream>>>(deg, partials, row_ptr, cursor, scalars);
  k_scatter<<<(E_EDGES + 255) / 256, 256, 0, stream>>>(src, dst, cursor, csr);

  // ----- layer 1 (conv fuses BN-stats accumulation)
  k_preab<false><<<768, 256, 0, stream>>>(h1, preW1, preb1, nullptr, nullptr,
                                          nullptr, nullptr, nullptr, hA, hB);
  k_conv<true><<<N_NODES / 8, 256, 0, stream>>>(hA, hB, h1, row_ptr, csr,
                                                postWT, postb1, linWT, linb1,
                                                scalars, y1, bnsum, bnsumsq);
  // ----- layer 2 (BN finalize + relu fused into preab staging)
  k_preab<true><<<768, 256, 0, stream>>>(y1, preW2, preb2, bnsum, bnsumsq,
                                         gamma, beta, h2, hA, hB);
  k_conv<false><<<N_NODES / 8, 256, 0, stream>>>(hA, hB, h2, row_ptr, csr,
                                                 postWT + 53248, postb2, linWT + 4096,
                                                 linb2, scalars, out, nullptr, nullptr);
}

// Round 10
// 536.138 us; speedup vs baseline: 1.9357x; 1.9357x over previous
//
#include <hip/hip_runtime.h>

#define N_NODES 50000
#define E_EDGES 800000
#define IN_F    128
#define H_F     64
#define STD_EPS 1e-5f
#define BN_EPS  1e-5f

#define HIST_BLK 3125   // E_EDGES / 256 exactly
#define EMB_BLK  768
#define SCAN_BLK 49
#define TRANS_BLK 448   // 114688 / 256

// ------------------------------------------- fused degree hist + embed GEMM
__global__ __launch_bounds__(256) void k_hist_embed(const int* __restrict__ dst,
                                                    int* __restrict__ deg,
                                                    const float* __restrict__ x,
                                                    const float* __restrict__ W,
                                                    const float* __restrict__ bias,
                                                    float* __restrict__ h) {
  __shared__ float sW[IN_F * 64];    // 32 KB
  __shared__ float sx[IN_F * 36];    // x_T[k][32+pad4] 18 KB
  if (blockIdx.x < HIST_BLK) {
    int e = blockIdx.x * 256 + threadIdx.x;
    atomicAdd(&deg[dst[e]], 1);      // grid sized so e < E_EDGES always
    return;
  }
  for (int i = threadIdx.x; i < IN_F * 64; i += 256) sW[i] = W[i];
  int f = threadIdx.x & 63, ng = threadIdx.x >> 6;
  float bj = bias[f];
  const int NGRP = (N_NODES + 31) / 32;   // 1563
  for (int grp = blockIdx.x - HIST_BLK; grp < NGRP; grp += EMB_BLK) {
    int n0 = grp * 32;
    __syncthreads();
    for (int idx = threadIdx.x; idx < 32 * IN_F; idx += 256) {
      int nl = idx >> 7, k = idx & 127;
      int n = n0 + nl;
      sx[k * 36 + nl] = (n < N_NODES) ? x[(size_t)n * IN_F + k] : 0.f;
    }
    __syncthreads();
    float a[8] = {bj, bj, bj, bj, bj, bj, bj, bj};
    const float* xp = &sx[ng * 8];
#pragma unroll 4
    for (int k = 0; k < IN_F; k++) {
      float4 h0 = *(const float4*)&xp[k * 36];
      float4 h1 = *(const float4*)&xp[k * 36 + 4];
      float w = sW[k * 64 + f];
      a[0] = fmaf(h0.x, w, a[0]); a[1] = fmaf(h0.y, w, a[1]);
      a[2] = fmaf(h0.z, w, a[2]); a[3] = fmaf(h0.w, w, a[3]);
      a[4] = fmaf(h1.x, w, a[4]); a[5] = fmaf(h1.y, w, a[5]);
      a[6] = fmaf(h1.z, w, a[6]); a[7] = fmaf(h1.w, w, a[7]);
    }
#pragma unroll
    for (int j = 0; j < 8; j++) {
      int n = n0 + ng * 8 + j;
      if (n < N_NODES) h[(size_t)n * 64 + f] = a[j];
    }
  }
}

// --------------------- fused scan phase-1 (+ sum log(deg+1)) and transpose
__global__ __launch_bounds__(256) void k_scanpart_trans(const int* __restrict__ deg,
                                                        int* __restrict__ partials,
                                                        float* __restrict__ scalars,
                                                        const float* __restrict__ pW1,
                                                        const float* __restrict__ pW2,
                                                        const float* __restrict__ lW1,
                                                        const float* __restrict__ lW2,
                                                        float* __restrict__ pWT,
                                                        float* __restrict__ lWT) {
  __shared__ int red[256];
  __shared__ float redf[256];
  if (blockIdx.x < SCAN_BLK) {
    int base = blockIdx.x * 1024;
    int s = 0; float ls = 0.f;
    for (int j = threadIdx.x; j < 1024; j += 256) {
      int i = base + j;
      if (i < N_NODES) { int d = deg[i]; s += d; ls += logf((float)d + 1.0f); }
    }
    red[threadIdx.x] = s; redf[threadIdx.x] = ls; __syncthreads();
    for (int st = 128; st > 0; st >>= 1) {
      if (threadIdx.x < st) {
        red[threadIdx.x] += red[threadIdx.x + st];
        redf[threadIdx.x] += redf[threadIdx.x + st];
      }
      __syncthreads();
    }
    if (threadIdx.x == 0) {
      partials[blockIdx.x] = red[0];
      atomicAdd(&scalars[0], redf[0]);
    }
    return;
  }
  int idx = (blockIdx.x - SCAN_BLK) * 256 + threadIdx.x;
  if (idx < 106496) {
    int layer = idx / 53248, r = idx % 53248;
    int t = r / 26624, r2 = r % 26624;
    int fb = r2 / 128, r3 = r2 % 128;
    int g = r3 / 4, j = r3 % 4;
    const float* srcp = layer ? pW2 : pW1;
    pWT[idx] = srcp[(size_t)t * 26624 + (fb * 4 + j) * 32 + g];
  } else if (idx < 114688) {
    int jj = idx - 106496;
    int layer = jj / 4096, r2 = jj % 4096;
    int c4 = r2 / 256, r3 = r2 % 256;
    int col = r3 / 4, j = r3 % 4;
    const float* srcl = layer ? lW2 : lW1;
    lWT[jj] = srcl[(c4 * 4 + j) * 64 + col];
  }
}

// ----------------------- scan final (self-computed prefix, no mid kernel)
__global__ __launch_bounds__(256) void k_scan_final(const int* __restrict__ deg,
                                                    const int* __restrict__ partials,
                                                    int* __restrict__ row_ptr,
                                                    int* __restrict__ cursor,
                                                    float* __restrict__ scalars) {
  __shared__ int ts[256];
  __shared__ int sbase;
  if (threadIdx.x == 0) {
    int pre = 0;
    for (int b = 0; b < (int)blockIdx.x; b++) pre += partials[b];
    sbase = pre;
    if (blockIdx.x == 0) {
      scalars[1] = scalars[0] / (float)N_NODES;   // avg_log
      row_ptr[N_NODES] = E_EDGES;
    }
  }
  int base = blockIdx.x * 1024 + threadIdx.x * 4;
  int d[4]; int s = 0;
#pragma unroll
  for (int j = 0; j < 4; j++) {
    int i = base + j;
    d[j] = (i < N_NODES) ? deg[i] : 0;
    s += d[j];
  }
  ts[threadIdx.x] = s; __syncthreads();
  for (int off = 1; off < 256; off <<= 1) {
    int t = (threadIdx.x >= off) ? ts[threadIdx.x - off] : 0;
    __syncthreads();
    ts[threadIdx.x] += t;
    __syncthreads();
  }
  int excl = (threadIdx.x > 0) ? ts[threadIdx.x - 1] : 0;
  int run = sbase + excl;
#pragma unroll
  for (int j = 0; j < 4; j++) {
    int i = base + j;
    if (i < N_NODES) { row_ptr[i] = run; cursor[i] = run; run += d[j]; }
  }
}

// ------------------------------------------------------------------- scatter
__global__ __launch_bounds__(256) void k_scatter(const int* __restrict__ src,
                                                 const int* __restrict__ dst,
                                                 int* __restrict__ cursor,
                                                 int* __restrict__ csr_src) {
  int e = blockIdx.x * 256 + threadIdx.x;
  if (e < E_EDGES) {
    int d = dst[e];
    int p = atomicAdd(&cursor[d], 1);
    csr_src[p] = src[e];
  }
}

// ------------------------------------------------------------------ pre A/B
// One TOWER per block (t = blockIdx.x & 1).  64-node groups, 16 nodes/thread.
// BN variant computes scale/shift itself from bnsum/bnsumsq (no k_bnfin).
template <bool BN>
__global__ __launch_bounds__(256) void k_preab(const float* __restrict__ hin,
                                               const float* __restrict__ preW,
                                               const float* __restrict__ preb,
                                               const float* __restrict__ bnsum,
                                               const float* __restrict__ bnsumsq,
                                               const float* __restrict__ gamma,
                                               const float* __restrict__ beta,
                                               float* __restrict__ h2out,
                                               float* __restrict__ hA,
                                               float* __restrict__ hB) {
  __shared__ float sWp[64 * 128];   // 32 KB packed [k][f][{A,B}]
  __shared__ float sh[64 * 68];     // h_T[k][64+pad4]  17408 B
  __shared__ float sbn[128];        // scale[64], shift[64]
  int t = blockIdx.x & 1;
  const float* Wsrc = preW + (size_t)t * 128 * 64;
  for (int i = threadIdx.x; i < 64 * 64; i += 256) {
    int k = i >> 6, f = i & 63;
    float wa = Wsrc[k * 64 + f];
    float wb = Wsrc[(64 + k) * 64 + f];
    *(float2*)&sWp[k * 128 + f * 2] = make_float2(wa, wb);
  }
  if (BN && threadIdx.x < 64) {
    int c = threadIdx.x;
    float mu = bnsum[c] * (1.f / N_NODES);
    float var = bnsumsq[c] * (1.f / N_NODES) - mu * mu;
    float sc = gamma[c] / sqrtf(var + BN_EPS);
    sbn[c] = sc;
    sbn[64 + c] = fmaf(-mu, sc, beta[c]);
  }
  int f = threadIdx.x & 63, ng = threadIdx.x >> 6;   // ng 0..3 -> 16 nodes each
  float pb = preb[t * 64 + f];
  int nblk2 = gridDim.x >> 1;
  const int NGRP = (N_NODES + 63) / 64;   // 782
  for (int grp = blockIdx.x >> 1; grp < NGRP; grp += nblk2) {
    int n0 = grp * 64;
    __syncthreads();
    for (int idx = threadIdx.x; idx < 64 * 64; idx += 256) {
      int nl = idx >> 6, k = idx & 63;
      int n = n0 + nl;
      float v = 0.f;
      if (n < N_NODES) {
        v = hin[(size_t)n * 64 + k];
        if (BN) {
          v = fmaxf(fmaf(v, sbn[k], sbn[64 + k]), 0.f);
          if (t == 0) h2out[(size_t)n * 64 + k] = v;
        }
      }
      sh[k * 68 + nl] = v;
    }
    __syncthreads();
    float a[16], b[16];
#pragma unroll
    for (int j = 0; j < 16; j++) { a[j] = pb; b[j] = 0.f; }
    const float* hp = &sh[ng * 16];
    const float* wp = &sWp[f * 2];
#pragma unroll 2
    for (int k = 0; k < 64; k++) {
      float4 h0 = *(const float4*)&hp[k * 68];
      float4 h1 = *(const float4*)&hp[k * 68 + 4];
      float4 h2 = *(const float4*)&hp[k * 68 + 8];
      float4 h3 = *(const float4*)&hp[k * 68 + 12];
      float2 w2 = *(const float2*)&wp[k * 128];
      a[0]  = fmaf(h0.x, w2.x, a[0]);  b[0]  = fmaf(h0.x, w2.y, b[0]);
      a[1]  = fmaf(h0.y, w2.x, a[1]);  b[1]  = fmaf(h0.y, w2.y, b[1]);
      a[2]  = fmaf(h0.z, w2.x, a[2]);  b[2]  = fmaf(h0.z, w2.y, b[2]);
      a[3]  = fmaf(h0.w, w2.x, a[3]);  b[3]  = fmaf(h0.w, w2.y, b[3]);
      a[4]  = fmaf(h1.x, w2.x, a[4]);  b[4]  = fmaf(h1.x, w2.y, b[4]);
      a[5]  = fmaf(h1.y, w2.x, a[5]);  b[5]  = fmaf(h1.y, w2.y, b[5]);
      a[6]  = fmaf(h1.z, w2.x, a[6]);  b[6]  = fmaf(h1.z, w2.y, b[6]);
      a[7]  = fmaf(h1.w, w2.x, a[7]);  b[7]  = fmaf(h1.w, w2.y, b[7]);
      a[8]  = fmaf(h2.x, w2.x, a[8]);  b[8]  = fmaf(h2.x, w2.y, b[8]);
      a[9]  = fmaf(h2.y, w2.x, a[9]);  b[9]  = fmaf(h2.y, w2.y, b[9]);
      a[10] = fmaf(h2.z, w2.x, a[10]); b[10] = fmaf(h2.z, w2.y, b[10]);
      a[11] = fmaf(h2.w, w2.x, a[11]); b[11] = fmaf(h2.w, w2.y, b[11]);
      a[12] = fmaf(h3.x, w2.x, a[12]); b[12] = fmaf(h3.x, w2.y, b[12]);
      a[13] = fmaf(h3.y, w2.x, a[13]); b[13] = fmaf(h3.y, w2.y, b[13]);
      a[14] = fmaf(h3.z, w2.x, a[14]); b[14] = fmaf(h3.z, w2.y, b[14]);
      a[15] = fmaf(h3.w, w2.x, a[15]); b[15] = fmaf(h3.w, w2.y, b[15]);
    }
    int tf = t * 64 + f;
#pragma unroll
    for (int j = 0; j < 16; j++) {
      int n = n0 + ng * 16 + j;
      if (n < N_NODES) {
        hA[(size_t)n * 128 + tf] = a[j];
        hB[(size_t)n * 128 + tf] = b[j];
      }
    }
  }
}

// --------------------------------------------------- fused conv main kernel
// 8 nodes/block, 20.5 KB LDS, 7 blocks/CU.  Packed transposed weights.
// (BN-stats fusion REVERTED: 1.6M same-address atomics serialized — R9.)
__global__ __launch_bounds__(256, 7) void k_conv(const float* __restrict__ hA,
                                                 const float* __restrict__ hB,
                                                 const float* __restrict__ hskip,
                                                 const int* __restrict__ row_ptr,
                                                 const int* __restrict__ csr_src,
                                                 const float* __restrict__ postWT,
                                                 const float* __restrict__ postb,
                                                 const float* __restrict__ linWT,
                                                 const float* __restrict__ linb,
                                                 const float* __restrict__ scalars,
                                                 float* __restrict__ out) {
  __shared__ float sm[2 * 5 * 8 * 64];   // 20480 B; [(t*5+feat)*512 + node*64 + hf]
  __shared__ float sAB[16];              // sA[0..7], sB[8..15]
  int w = threadIdx.x >> 6, lane = threadIdx.x & 63;
  int n0 = blockIdx.x * 8;
  int t = lane >> 5, fb2 = (lane & 31) * 2;
  int off = t * 64 + fb2;
  float avg = scalars[1];

  // ---- phase A: aggregation, 2 nodes per wave, 4 loads in flight
#pragma unroll 1
  for (int k = 0; k < 2; k++) {
    int nl = w * 2 + k;
    int n = n0 + nl;
    float2 a = *(const float2*)&hA[(size_t)n * 128 + off];
    int rp0 = __builtin_amdgcn_readfirstlane(row_ptr[n]);
    int rp1 = __builtin_amdgcn_readfirstlane(row_ptr[n + 1]);
    float sx0=0,sy0=0,qx0=0,qy0=0, sx1=0,sy1=0,qx1=0,qy1=0;
    float mnx0=INFINITY,mny0=INFINITY,mxx0=-INFINITY,mxy0=-INFINITY;
    float mnx1=INFINITY,mny1=INFINITY,mxx1=-INFINITY,mxy1=-INFINITY;
    int i = rp0;
    int end4 = rp0 + ((rp1 - rp0) & ~3);
    if (i < end4) {
      int s0 = csr_src[i], s1 = csr_src[i+1], s2 = csr_src[i+2], s3 = csr_src[i+3];
      while (true) {
        float2 v0 = *(const float2*)&hB[(size_t)s0 * 128 + off];
        float2 v1 = *(const float2*)&hB[(size_t)s1 * 128 + off];
        float2 v2 = *(const float2*)&hB[(size_t)s2 * 128 + off];
        float2 v3 = *(const float2*)&hB[(size_t)s3 * 128 + off];
        i += 4;
        bool more = (i < end4);
        if (more) { s0 = csr_src[i]; s1 = csr_src[i+1]; s2 = csr_src[i+2]; s3 = csr_src[i+3]; }
        float e0x = v0.x + a.x, e0y = v0.y + a.y;
        float e1x = v1.x + a.x, e1y = v1.y + a.y;
        float e2x = v2.x + a.x, e2y = v2.y + a.y;
        float e3x = v3.x + a.x, e3y = v3.y + a.y;
        sx0 += e0x; qx0 = fmaf(e0x,e0x,qx0); mnx0 = fminf(mnx0,e0x); mxx0 = fmaxf(mxx0,e0x);
        sy0 += e0y; qy0 = fmaf(e0y,e0y,qy0); mny0 = fminf(mny0,e0y); mxy0 = fmaxf(mxy0,e0y);
        sx1 += e1x; qx1 = fmaf(e1x,e1x,qx1); mnx1 = fminf(mnx1,e1x); mxx1 = fmaxf(mxx1,e1x);
        sy1 += e1y; qy1 = fmaf(e1y,e1y,qy1); mny1 = fminf(mny1,e1y); mxy1 = fmaxf(mxy1,e1y);
        sx0 += e2x; qx0 = fmaf(e2x,e2x,qx0); mnx0 = fminf(mnx0,e2x); mxx0 = fmaxf(mxx0,e2x);
        sy0 += e2y; qy0 = fmaf(e2y,e2y,qy0); mny0 = fminf(mny0,e2y); mxy0 = fmaxf(mxy0,e2y);
        sx1 += e3x; qx1 = fmaf(e3x,e3x,qx1); mnx1 = fminf(mnx1,e3x); mxx1 = fmaxf(mxx1,e3x);
        sy1 += e3y; qy1 = fmaf(e3y,e3y,qy1); mny1 = fminf(mny1,e3y); mxy1 = fmaxf(mxy1,e3y);
        if (!more) break;
      }
    }
    {   // masked tail: 0..3 edges, all loads issued together
      int r = rp1 - i;
      if (r > 0) {
        int e1i = (r > 1) ? i + 1 : i;
        int e2i = (r > 2) ? i + 2 : i;
        int t0 = csr_src[i], t1 = csr_src[e1i], t2 = csr_src[e2i];
        float2 u0 = *(const float2*)&hB[(size_t)t0 * 128 + off];
        float2 u1 = *(const float2*)&hB[(size_t)t1 * 128 + off];
        float2 u2 = *(const float2*)&hB[(size_t)t2 * 128 + off];
        float ex = u0.x + a.x, ey = u0.y + a.y;
        sx0 += ex; qx0 = fmaf(ex,ex,qx0); mnx0 = fminf(mnx0,ex); mxx0 = fmaxf(mxx0,ex);
        sy0 += ey; qy0 = fmaf(ey,ey,qy0); mny0 = fminf(mny0,ey); mxy0 = fmaxf(mxy0,ey);
        if (r > 1) {
          ex = u1.x + a.x; ey = u1.y + a.y;
          sx1 += ex; qx1 = fmaf(ex,ex,qx1); mnx1 = fminf(mnx1,ex); mxx1 = fmaxf(mxx1,ex);
          sy1 += ey; qy1 = fmaf(ey,ey,qy1); mny1 = fminf(mny1,ey); mxy1 = fmaxf(mxy1,ey);
        }
        if (r > 2) {
          ex = u2.x + a.x; ey = u2.y + a.y;
          sx0 += ex; qx0 = fmaf(ex,ex,qx0); mnx0 = fminf(mnx0,ex); mxx0 = fmaxf(mxx0,ex);
          sy0 += ey; qy0 = fmaf(ey,ey,qy0); mny0 = fminf(mny0,ey); mxy0 = fmaxf(mxy0,ey);
        }
      }
    }
    int dg = rp1 - rp0;
    float cnt = (float)(dg > 0 ? dg : 1);
    float inv = 1.0f / cnt;
    float meanx = (sx0 + sx1) * inv, meany = (sy0 + sy1) * inv;
    float qx = qx0 + qx1, qy = qy0 + qy1;
    float sdx = sqrtf(fmaxf(qx * inv - meanx * meanx, 0.f) + STD_EPS);
    float sdy = sqrtf(fmaxf(qy * inv - meany * meany, 0.f) + STD_EPS);
    float mnx = fminf(mnx0, mnx1), mny = fminf(mny0, mny1);
    float mxx = fmaxf(mxx0, mxx1), mxy = fmaxf(mxy0, mxy1);
    if (dg == 0) { mnx = 0; mny = 0; mxx = 0; mxy = 0; }
    float ldv = logf(cnt + 1.f);
    float2 hsv = *(const float2*)&hskip[(size_t)n * 64 + fb2];
    // write 5 unique slices
    float* bp = &sm[t * 2560 + nl * 64 + fb2];
    *(float2*)&bp[0]    = hsv;
    *(float2*)&bp[512]  = make_float2(meanx, meany);
    *(float2*)&bp[1024] = make_float2(mnx, mny);
    *(float2*)&bp[1536] = make_float2(mxx, mxy);
    *(float2*)&bp[2048] = make_float2(sdx, sdy);
    if (lane == 0) { sAB[nl] = ldv / avg; sAB[8 + nl] = avg / ldv; }
  }
  __syncthreads();

  // ---- phase C: factored post matmul; wave w covers hf [w*16, w*16+16)
  float g1[8] = {0,0,0,0,0,0,0,0};
  float g2[8] = {0,0,0,0,0,0,0,0};
  float g3[8] = {0,0,0,0,0,0,0,0};
  {
    int g = lane & 31, hf0 = w * 16, fb0 = w * 4;
    const float4* pw4 = (const float4*)postWT + (size_t)t * 6656 + g;
    const float* vb = &sm[t * 2560 + hf0];
    // feat0 = h: G1 only
#pragma unroll
    for (int jj = 0; jj < 4; jj++) {
      float4 wv = pw4[(fb0 + jj) * 32];
#pragma unroll
      for (int nn = 0; nn < 8; nn++) {
        float4 v = *(const float4*)&vb[nn * 64 + jj * 4];
        g1[nn] = fmaf(v.w, wv.w, fmaf(v.z, wv.z, fmaf(v.y, wv.y, fmaf(v.x, wv.x, g1[nn]))));
      }
    }
    // feats 1..4 (agg): fb = 16+fa*16+fb0+jj; G2 at +64 fb, G3 at +128 fb
#pragma unroll
    for (int fa = 0; fa < 4; fa++) {
      const float* vfa = &vb[(1 + fa) * 512];
#pragma unroll
      for (int jj = 0; jj < 4; jj++) {
        int fb = 16 + fa * 16 + fb0 + jj;
        float4 w1v = pw4[fb * 32];
        float4 w2v = pw4[(fb + 64) * 32];
        float4 w3v = pw4[(fb + 128) * 32];
#pragma unroll
        for (int nn = 0; nn < 8; nn++) {
          float4 v = *(const float4*)&vfa[nn * 64 + jj * 4];
          g1[nn] = fmaf(v.w, w1v.w, fmaf(v.z, w1v.z, fmaf(v.y, w1v.y, fmaf(v.x, w1v.x, g1[nn]))));
          g2[nn] = fmaf(v.w, w2v.w, fmaf(v.z, w2v.z, fmaf(v.y, w2v.y, fmaf(v.x, w2v.x, g2[nn]))));
          g3[nn] = fmaf(v.w, w3v.w, fmaf(v.z, w3v.z, fmaf(v.y, w3v.y, fmaf(v.x, w3v.x, g3[nn]))));
        }
      }
    }
  }
  // combine with per-node scalars (sAB reads are broadcast)
  float o8[8];
#pragma unroll
  for (int nn = 0; nn < 8; nn++)
    o8[nn] = fmaf(sAB[8 + nn], g3[nn], fmaf(sAB[nn], g2[nn], g1[nn]));
  __syncthreads();   // all sm reads done -> safe to alias

  // ---- partials into aliased region: lpart[node8][tg64][rep4] = sm[0..2047]
  {
    int sw = (w + (lane >> 4)) & 3;
#pragma unroll
    for (int nn = 0; nn < 8; nn++)
      sm[((nn * 64 + lane) << 2) + sw] = o8[nn];
  }
  __syncthreads();

  // ---- reduce + postb -> po at sm[2048 + node*64 + col]
  {
#pragma unroll
    for (int r = 0; r < 2; r++) {
      int idx = r * 256 + (int)threadIdx.x;
      float4 p = *(const float4*)&sm[idx << 2];
      sm[2048 + idx] = p.x + p.y + p.z + p.w + postb[idx & 63];
    }
  }
  __syncthreads();

  // ---- lin epilogue: wave w -> nodes w*2, w*2+1; col = lane
  {
    float acc0 = linb[lane], acc1 = acc0;
    const float4* lw4 = (const float4*)linWT + lane;
    const float* p0 = &sm[2048 + (w * 2) * 64];
    const float* p1 = p0 + 64;
#pragma unroll
    for (int c4 = 0; c4 < 16; c4++) {
      float4 lwv = lw4[c4 * 64];
      float4 pa = *(const float4*)&p0[c4 * 4];
      float4 pb2 = *(const float4*)&p1[c4 * 4];
      acc0 = fmaf(pa.w, lwv.w, fmaf(pa.z, lwv.z, fmaf(pa.y, lwv.y, fmaf(pa.x, lwv.x, acc0))));
      acc1 = fmaf(pb2.w, lwv.w, fmaf(pb2.z, lwv.z, fmaf(pb2.y, lwv.y, fmaf(pb2.x, lwv.x, acc1))));
    }
    size_t ob = (size_t)(n0 + w * 2) * 64 + lane;
    out[ob] = acc0;
    out[ob + 64] = acc1;
  }
}

// ------------------------------------------------------------------ BN stats
// Pre-reduced per block: 256 blocks x 64 atomics = 16k atomics total.
__global__ __launch_bounds__(256) void k_bnstats(const float* __restrict__ y,
                                                 float* __restrict__ bnsum,
                                                 float* __restrict__ bnsumsq) {
  __shared__ float r1[256], r2[256];
  int c = threadIdx.x & 63, r = threadIdx.x >> 6;
  float s = 0, q = 0;
  for (int n = blockIdx.x * 4 + r; n < N_NODES; n += gridDim.x * 4) {
    float v = y[(size_t)n * 64 + c];
    s += v; q = fmaf(v, v, q);
  }
  r1[threadIdx.x] = s; r2[threadIdx.x] = q; __syncthreads();
  if (threadIdx.x < 64) {
    s = r1[threadIdx.x] + r1[threadIdx.x + 64] + r1[threadIdx.x + 128] + r1[threadIdx.x + 192];
    q = r2[threadIdx.x] + r2[threadIdx.x + 64] + r2[threadIdx.x + 128] + r2[threadIdx.x + 192];
    atomicAdd(&bnsum[threadIdx.x], s);
    atomicAdd(&bnsumsq[threadIdx.x], q);
  }
}

// ================================================================== launcher
extern "C" void kernel_launch(void* const* d_in, const int* in_sizes, int n_in,
                              void* d_out, int out_size, void* d_ws, size_t ws_size,
                              hipStream_t stream) {
  const float* x      = (const float*)d_in[0];
  const float* embW   = (const float*)d_in[1];
  const float* embB   = (const float*)d_in[2];
  const float* preW1  = (const float*)d_in[3];
  const float* preb1  = (const float*)d_in[4];
  const float* postW1 = (const float*)d_in[5];
  const float* postb1 = (const float*)d_in[6];
  const float* linW1  = (const float*)d_in[7];
  const float* linb1  = (const float*)d_in[8];
  const float* gamma  = (const float*)d_in[9];
  const float* beta   = (const float*)d_in[10];
  const float* preW2  = (const float*)d_in[11];
  const float* preb2  = (const float*)d_in[12];
  const float* postW2 = (const float*)d_in[13];
  const float* postb2 = (const float*)d_in[14];
  const float* linW2  = (const float*)d_in[15];
  const float* linb2  = (const float*)d_in[16];
  const int*   src    = (const int*)d_in[17];
  const int*   dst    = (const int*)d_in[18];
  float* out = (float*)d_out;

  char* w = (char*)d_ws;
  size_t o = 0;
  int*   deg     = (int*)(w + o);   o += (size_t)N_NODES * 4;
  float* scalars = (float*)(w + o); o += 64;
  float* bnsum   = (float*)(w + o); o += 256;
  float* bnsumsq = (float*)(w + o); o += 256;
  size_t zero_len = o;
  o = (o + 255) & ~(size_t)255;
  int* partials = (int*)(w + o);  o += 256;
  int* row_ptr  = (int*)(w + o);  o += (size_t)(N_NODES + 1) * 4; o = (o + 255) & ~(size_t)255;
  int* cursor   = (int*)(w + o);  o += (size_t)N_NODES * 4;       o = (o + 255) & ~(size_t)255;
  int* csr      = (int*)(w + o);  o += (size_t)E_EDGES * 4;       o = (o + 255) & ~(size_t)255;
  float* postWT = (float*)(w + o); o += (size_t)2 * 53248 * 4;
  float* linWT  = (float*)(w + o); o += (size_t)2 * 4096 * 4;
  float* h1 = (float*)(w + o); o += (size_t)N_NODES * 64 * 4;
  float* y1 = (float*)(w + o); o += (size_t)N_NODES * 64 * 4;
  float* h2 = (float*)(w + o); o += (size_t)N_NODES * 64 * 4;
  float* hA = (float*)(w + o); o += (size_t)N_NODES * 128 * 4;
  float* hB = (float*)(w + o); o += (size_t)N_NODES * 128 * 4;

  hipMemsetAsync(w, 0, zero_len, stream);

  // hist + embed (fused, independent)
  k_hist_embed<<<HIST_BLK + EMB_BLK, 256, 0, stream>>>(dst, deg, x, embW, embB, h1);
  // scan phase 1 + log-sum + weight transpose (fused, independent)
  k_scanpart_trans<<<SCAN_BLK + TRANS_BLK, 256, 0, stream>>>(
      deg, partials, scalars, postW1, postW2, linW1, linW2, postWT, linWT);
  k_scan_final<<<SCAN_BLK, 256, 0, stream>>>(deg, partials, row_ptr, cursor, scalars);
  k_scatter<<<(E_EDGES + 255) / 256, 256, 0, stream>>>(src, dst, cursor, csr);

  // ----- layer 1
  k_preab<false><<<768, 256, 0, stream>>>(h1, preW1, preb1, nullptr, nullptr,
                                          nullptr, nullptr, nullptr, hA, hB);
  k_conv<<<N_NODES / 8, 256, 0, stream>>>(hA, hB, h1, row_ptr, csr,
                                          postWT, postb1, linWT, linb1, scalars, y1);
  k_bnstats<<<256, 256, 0, stream>>>(y1, bnsum, bnsumsq);
  // ----- layer 2 (BN finalize + relu fused into preab staging)
  k_preab<true><<<768, 256, 0, stream>>>(y1, preW2, preb2, bnsum, bnsumsq,
                                         gamma, beta, h2, hA, hB);
  k_conv<<<N_NODES / 8, 256, 0, stream>>>(hA, hB, h2, row_ptr, csr,
                                          postWT + 53248, postb2, linWT + 4096,
                                          linb2, scalars, out);
}